// Round 8
// baseline (222.969 us; speedup 1.0000x reference)
//
#include <hip/hip_runtime.h>
#include <math.h>

#define NB 4
#define NC 256
#define NHEADS 4
#define DH 64
#define NT 4096            // 64*64 tokens per batch
// q pre-scale with log2(e) folded in: exp(s/8) == exp2(s * QSCALE)
#define QSCALE (0.125f * 1.44269504088896f)

typedef __bf16  bf16x8 __attribute__((ext_vector_type(8)));
typedef __bf16  bf16x4 __attribute__((ext_vector_type(4)));
typedef float   f32x4  __attribute__((ext_vector_type(4)));
typedef short   s16x8  __attribute__((ext_vector_type(8)));

static __device__ __forceinline__ unsigned short f2bf(float f) {
    unsigned u = __float_as_uint(f);
    u = (u + 0x7fffu + ((u >> 16) & 1u)) >> 16;   // round-to-nearest-even
    return (unsigned short)u;
}

// async 16B/lane global -> LDS (DMA, no VGPR round-trip).
static __device__ __forceinline__ void gload16(const unsigned short* g, unsigned short* l) {
    __builtin_amdgcn_global_load_lds((const __attribute__((address_space(1))) void*)g,
                                     (__attribute__((address_space(3))) void*)l, 16, 0, 0);
}

// Stage 64 rows x 256 bf16 (global row stride 256 elems) -> LDS stride 264.
static __device__ __forceinline__ void stage_64x256(
    unsigned short* __restrict__ lds, const unsigned short* __restrict__ g, int tid)
{
    #pragma unroll
    for (int chunk = 0; chunk < 8; ++chunk) {
        const int row = chunk * 8 + (tid >> 5);
        const int col = (tid & 31) * 8;
        *(s16x8*)&lds[row * 264 + col] = *(const s16x8*)&g[row * 256 + col];
    }
}

// ---------------------------------------------------------------------------
// Kernel 0: weight prep (unchanged).
// ---------------------------------------------------------------------------
__global__ __launch_bounds__(256) void k_prep(
    const float* __restrict__ wqkv, const float* __restrict__ wproj,
    unsigned short* __restrict__ wqkv_t, unsigned short* __restrict__ wproj_bf)
{
    const int id = blockIdx.x;
    const int tid = threadIdx.x;
    if (id < 48) {
        __shared__ float T[64][65];
        const int jt = id % 12, ct = id / 12;
        #pragma unroll
        for (int p = 0; p < 16; ++p) {
            const int idx = tid + (p << 8);
            const int r = idx >> 6, cl = idx & 63;
            T[r][cl] = wqkv[(size_t)(ct * 64 + r) * 768 + jt * 64 + cl];
        }
        __syncthreads();
        #pragma unroll
        for (int p = 0; p < 16; ++p) {
            const int idx = tid + (p << 8);
            const int r = idx >> 6, cl = idx & 63;
            wqkv_t[(size_t)(jt * 64 + r) * 256 + ct * 64 + cl] = f2bf(T[cl][r]);
        }
    } else {
        const int base = (id - 48) * 2048 + tid * 8;
        s16x8 v;
        #pragma unroll
        for (int j = 0; j < 8; ++j) v[j] = (short)f2bf(wproj[base + j]);
        *(s16x8*)&wproj_bf[base] = v;
    }
}

// ---------------------------------------------------------------------------
// Kernel 1: LayerNorm + QKV GEMM via bf16 MFMA. (unchanged from R7)
// ---------------------------------------------------------------------------
__global__ __launch_bounds__(256) void k_ln_qkv(
    const float* __restrict__ x,       // [B][C][N]
    const float* __restrict__ ln_g,
    const float* __restrict__ ln_b,
    const unsigned short* __restrict__ wqkv_t,  // [768][256] bf16
    unsigned short* __restrict__ q_bf,
    unsigned short* __restrict__ k_bf,
    unsigned short* __restrict__ v_bf)
{
    __shared__ unsigned short An[64 * 264];
    __shared__ unsigned short Wt[64 * 264];
    __shared__ float red1[4][64], red2[4][64];
    __shared__ float mu_s[64], rs_s[64];

    const int b     = blockIdx.x >> 6;
    const int n0    = (blockIdx.x & 63) << 6;
    const int three = blockIdx.y;
    const int tid   = threadIdx.x;
    const int li    = tid & 63;
    const int grp   = tid >> 6;
    const int w     = grp;
    const int lane  = li;
    const int q4    = lane >> 4;
    const int c     = lane & 15;

    const float* xb = x + ((size_t)b * NC) * NT + n0 + li;

    float xr[64];
    #pragma unroll
    for (int chunk = 0; chunk < 8; ++chunk)
        #pragma unroll
        for (int j = 0; j < 8; ++j)
            xr[chunk * 8 + j] = xb[(size_t)(chunk * 32 + grp * 8 + j) * NT];

    float s1 = 0.f, s2 = 0.f;
    #pragma unroll
    for (int i = 0; i < 64; ++i) { s1 += xr[i]; s2 += xr[i] * xr[i]; }
    red1[grp][li] = s1; red2[grp][li] = s2;
    __syncthreads();
    if (tid < 64) {
        const float t1 = red1[0][tid] + red1[1][tid] + red1[2][tid] + red1[3][tid];
        const float t2 = red2[0][tid] + red2[1][tid] + red2[2][tid] + red2[3][tid];
        const float mu  = t1 * (1.0f / NC);
        const float var = t2 * (1.0f / NC) - mu * mu;
        mu_s[tid] = mu;
        rs_s[tid] = rsqrtf(var + 1e-5f);
    }
    __syncthreads();
    const float mu = mu_s[li];
    const float rs = rs_s[li];

    #pragma unroll
    for (int chunk = 0; chunk < 8; ++chunk) {
        s16x8 pk;
        #pragma unroll
        for (int j = 0; j < 8; ++j) {
            const int ch = chunk * 32 + grp * 8 + j;
            const float vv = (xr[chunk * 8 + j] - mu) * rs * ln_g[ch] + ln_b[ch];
            pk[j] = (short)f2bf(vv);
        }
        *(s16x8*)&An[li * 264 + chunk * 32 + grp * 8] = pk;
    }
    __syncthreads();

    bf16x8 aT[8];
    if (three < 2) {
        #pragma unroll
        for (int kt = 0; kt < 8; ++kt)
            aT[kt] = *(const bf16x8*)&An[(16 * w + c) * 264 + kt * 32 + q4 * 8];
    }

    for (int jt = 0; jt < 4; ++jt) {
        __syncthreads();
        stage_64x256(Wt, wqkv_t + (size_t)(three * 256 + jt * 64) * 256, tid);
        __syncthreads();

        f32x4 acc[4];
        #pragma unroll
        for (int nt = 0; nt < 4; ++nt)
            #pragma unroll
            for (int r = 0; r < 4; ++r) acc[nt][r] = 0.f;

        const int bh = b * NHEADS + jt;
        if (three < 2) {
            #pragma unroll
            for (int nt = 0; nt < 4; ++nt)
                #pragma unroll
                for (int kt = 0; kt < 8; ++kt) {
                    const bf16x8 bb = *(const bf16x8*)&Wt[(16 * nt + c) * 264 + kt * 32 + q4 * 8];
                    acc[nt] = __builtin_amdgcn_mfma_f32_16x16x32_bf16(aT[kt], bb, acc[nt], 0, 0, 0);
                }
            unsigned short* dst = (three == 0 ? q_bf : k_bf) + ((size_t)bh * NT + n0) * DH;
            const float sc = (three == 0) ? QSCALE : 1.0f;
            #pragma unroll
            for (int nt = 0; nt < 4; ++nt)
                #pragma unroll
                for (int r = 0; r < 4; ++r)
                    dst[(size_t)(16 * w + 4 * q4 + r) * DH + 16 * nt + c] = f2bf(acc[nt][r] * sc);
        } else {
            bf16x8 aW[8];
            #pragma unroll
            for (int kt = 0; kt < 8; ++kt)
                aW[kt] = *(const bf16x8*)&Wt[(16 * w + c) * 264 + kt * 32 + q4 * 8];
            #pragma unroll
            for (int nt = 0; nt < 4; ++nt)
                #pragma unroll
                for (int kt = 0; kt < 8; ++kt) {
                    const bf16x8 bb = *(const bf16x8*)&An[(16 * nt + c) * 264 + kt * 32 + q4 * 8];
                    acc[nt] = __builtin_amdgcn_mfma_f32_16x16x32_bf16(aW[kt], bb, acc[nt], 0, 0, 0);
                }
            unsigned short* dst = v_bf + (size_t)bh * DH * NT;
            #pragma unroll
            for (int nt = 0; nt < 4; ++nt)
                #pragma unroll
                for (int r = 0; r < 4; ++r)
                    dst[(size_t)(16 * w + 4 * q4 + r) * NT + n0 + 16 * nt + c] = f2bf(acc[nt][r]);
        }
    }
}

// ---------------------------------------------------------------------------
// Kernel 2: split-K bf16-MFMA flash attention, S^T formulation, DOUBLE-
// buffered async DMA staging (issue after barrier; one vmcnt(0);s_barrier
// per iter). Each block: 128 queries x 2048 keys. Unnormalized partial O
// (f32) + l partials to workspace. Max-free softmax via exp2.
// grid = 16 bh * 32 qtiles * 2 khalf = 1024 blocks -> 3 blocks/CU (LDS).
// LDS: K 2*8KB + V 2*8KB + Ps(bf16 128x72) 18432 = 50176 B.
// ---------------------------------------------------------------------------
__global__ __launch_bounds__(256, 2) void k_attn(
    const unsigned short* __restrict__ qg,  // [bh][n][d], pre-scaled by QSCALE
    const unsigned short* __restrict__ kg,  // [bh][n][d]
    const unsigned short* __restrict__ vg,  // [bh][d][n]  (transposed)
    float* __restrict__ o_part,             // [2][16][4096][64] f32, unnormalized
    float* __restrict__ l_part)             // [2][16][4096] f32
{
    __shared__ unsigned short Ks[2 * 4096];
    __shared__ unsigned short Vt[2 * 4096];
    __shared__ __bf16 Ps[128 * 72];

    const int bh   = blockIdx.x >> 6;          // 0..15
    const int rest = blockIdx.x & 63;
    const int qt   = rest >> 1;                // 0..31
    const int kh   = rest & 1;                 // K half
    const int n0   = qt << 7;                  // 128-query tile base
    const int tid  = threadIdx.x;
    const int w    = tid >> 6;                 // wave -> query rows 32w..32w+31
    const int lane = tid & 63;
    const int q4   = lane >> 4;
    const int c    = lane & 15;

    const unsigned short* kb = kg + ((size_t)bh * NT + (kh << 11)) * DH;
    const unsigned short* vb = vg + (size_t)bh * DH * NT + (kh << 11);

    // ---- Q frags direct from global (lane&15 = query, 8 d-elems each) ----
    bf16x8 aq[2][2];
    {
        const unsigned short* qp = qg + ((size_t)bh * NT + n0) * DH;
        #pragma unroll
        for (int g = 0; g < 2; ++g) {
            const unsigned short* qrow = qp + (size_t)(32 * w + 16 * g + c) * DH;
            aq[g][0] = *(const bf16x8*)(qrow + q4 * 8);
            aq[g][1] = *(const bf16x8*)(qrow + 32 + q4 * 8);
        }
    }

    // ---- staging lane geometry (per 1KB DMA instruction) ----
    const int rr = lane >> 3;                  // row within 8-row group
    const int kc = (lane & 7) ^ rr;            // swizzled 16B-chunk column
    const int koffK = rr * DH + kc * 8;

    // ---- swizzled frag-read offsets ----
    const int sw0 = ((q4    ) ^ (c & 7)) * 8;  // chunk q4   (d 0..31)
    const int sw1 = ((q4 + 4) ^ (c & 7)) * 8;  // chunk q4+4 (d 32..63)

    #define ISSUE_TILE(it_, bi_)                                               \
        {                                                                      \
            const unsigned short* ktp = kb + (size_t)(it_) * 64 * DH;          \
            const unsigned short* vtp = vb + (size_t)(it_) * 64;               \
            _Pragma("unroll")                                                  \
            for (int t = 0; t < 2; ++t) {                                      \
                const int grp_ = w * 2 + t;                                    \
                gload16(ktp + grp_ * 512 + koffK,                              \
                        &Ks[(bi_) * 4096 + grp_ * 512 + lane * 8]);            \
                gload16(vtp + (size_t)(grp_ * 8 + rr) * NT + kc * 8,           \
                        &Vt[(bi_) * 4096 + grp_ * 512 + lane * 8]);            \
            }                                                                  \
        }

    ISSUE_TILE(0, 0)

    f32x4 oac[2][4];
    #pragma unroll
    for (int g = 0; g < 2; ++g)
        #pragma unroll
        for (int dt = 0; dt < 4; ++dt)
            #pragma unroll
            for (int r = 0; r < 4; ++r) oac[g][dt][r] = 0.f;
    float lsum[2][4] = {};   // per-lane l partials (query c, keys {16nt+4q4+r})

    for (int it = 0; it < 32; ++it) {
        const int cur = it & 1;
        // own tile-it DMAs (issued last iter) done; barrier => whole tile
        // staged AND everyone finished reading the buffer we overwrite next.
        asm volatile("s_waitcnt vmcnt(0)\n\ts_barrier" ::: "memory");
        if (it < 31) ISSUE_TILE(it + 1, cur ^ 1)

        const unsigned short* Kb = &Ks[cur * 4096];
        const unsigned short* Vb = &Vt[cur * 4096];

        // ---- S^T = K Q^T: A = K-frag (m=key), B = Q-frag (n=query) ----
        f32x4 st[2][4];
        #pragma unroll
        for (int nt = 0; nt < 4; ++nt) {
            const bf16x8 kf0 = *(const bf16x8*)&Kb[(16 * nt + c) * 64 + sw0];
            const bf16x8 kf1 = *(const bf16x8*)&Kb[(16 * nt + c) * 64 + sw1];
            #pragma unroll
            for (int g = 0; g < 2; ++g) {
                f32x4 acc;
                #pragma unroll
                for (int r = 0; r < 4; ++r) acc[r] = 0.f;
                acc = __builtin_amdgcn_mfma_f32_16x16x32_bf16(kf0, aq[g][0], acc, 0, 0, 0);
                acc = __builtin_amdgcn_mfma_f32_16x16x32_bf16(kf1, aq[g][1], acc, 0, 0, 0);
                st[g][nt] = acc;
            }
        }

        // ---- P = exp2(S); pack 4 consecutive keys -> one ds_write_b64 ----
        #pragma unroll
        for (int g = 0; g < 2; ++g)
            #pragma unroll
            for (int nt = 0; nt < 4; ++nt) {
                bf16x4 pk;
                #pragma unroll
                for (int r = 0; r < 4; ++r) {
                    const float e = exp2f(st[g][nt][r]);
                    lsum[g][nt] += e;
                    pk[r] = (__bf16)e;
                }
                *(bf16x4*)&Ps[(32 * w + 16 * g + c) * 72 + 16 * nt + 4 * q4] = pk;
            }

        // ---- PV: A = P (m=query, b128 rows), B = V^T frags (shared) ----
        bf16x8 pa[2][2];
        #pragma unroll
        for (int g = 0; g < 2; ++g) {
            const __bf16* prow = &Ps[(32 * w + 16 * g + c) * 72];
            pa[g][0] = *(const bf16x8*)(prow + q4 * 8);
            pa[g][1] = *(const bf16x8*)(prow + 32 + q4 * 8);
        }
        #pragma unroll
        for (int dt = 0; dt < 4; ++dt) {
            const bf16x8 v0 = *(const bf16x8*)&Vb[(16 * dt + c) * 64 + sw0];
            const bf16x8 v1 = *(const bf16x8*)&Vb[(16 * dt + c) * 64 + sw1];
            #pragma unroll
            for (int g = 0; g < 2; ++g) {
                oac[g][dt] = __builtin_amdgcn_mfma_f32_16x16x32_bf16(pa[g][0], v0, oac[g][dt], 0, 0, 0);
                oac[g][dt] = __builtin_amdgcn_mfma_f32_16x16x32_bf16(pa[g][1], v1, oac[g][dt], 0, 0, 0);
            }
        }
    }
    #undef ISSUE_TILE

    // ---- write unnormalized partial O (f32) and per-query l partial ----
    float* op = o_part + (((size_t)kh * 16 + bh) * NT + n0 + 32 * w) * DH;
    #pragma unroll
    for (int g = 0; g < 2; ++g)
        #pragma unroll
        for (int dt = 0; dt < 4; ++dt)
            #pragma unroll
            for (int r = 0; r < 4; ++r)
                op[(size_t)(16 * g + 4 * q4 + r) * DH + 16 * dt + c] = oac[g][dt][r];

    float* lp = l_part + ((size_t)kh * 16 + bh) * NT + n0 + 32 * w;
    #pragma unroll
    for (int g = 0; g < 2; ++g) {
        float t = (lsum[g][0] + lsum[g][1]) + (lsum[g][2] + lsum[g][3]);
        t += __shfl_xor(t, 16);
        t += __shfl_xor(t, 32);
        if (q4 == 0) lp[16 * g + c] = t;     // lanes 0..15 -> 16 consecutive f32
    }
}

// ---------------------------------------------------------------------------
// Kernel 3: output projection via bf16 MFMA with FUSED split-K combine:
// stages O from the two unnormalized partials + l during the LDS build.
// grid = (NB*64, 4).
// ---------------------------------------------------------------------------
__global__ __launch_bounds__(256) void k_proj(
    const float* __restrict__ o_part,            // [2][16][4096][64] f32
    const float* __restrict__ l_part,            // [2][16][4096] f32
    const unsigned short* __restrict__ wproj_bf, // [256][256] bf16
    const float* __restrict__ b_proj,
    float* __restrict__ out)                     // [B][C][N]
{
    __shared__ unsigned short Os[64 * 264];
    __shared__ unsigned short Ws[64 * 264];

    const int b   = blockIdx.x >> 6;
    const int n0  = (blockIdx.x & 63) << 6;
    const int cg0 = blockIdx.y << 6;
    const int tid = threadIdx.x;
    const int w   = tid >> 6;
    const int lane = tid & 63;
    const int q4  = lane >> 4;
    const int c   = lane & 15;

    const size_t OPS = (size_t)16 * NT * DH;     // o_part kh-stride
    const size_t LPS = (size_t)16 * NT;          // l_part kh-stride

    // ---- stage combined O tile: (O0+O1)/(l0+l1) -> bf16 LDS ----
    #pragma unroll
    for (int chunk = 0; chunk < 8; ++chunk) {
        const int row = chunk * 8 + (tid >> 5);
        const int col = (tid & 31) * 8;
        const int hd  = col >> 6;
        const int c64 = col & 63;
        const size_t tok = (size_t)(b * NHEADS + hd) * NT + n0 + row;
        const float rv = 1.0f / (l_part[tok] + l_part[LPS + tok]);
        const float* p0 = o_part + tok * DH + c64;
        const float* p1 = p0 + OPS;
        const f32x4 a0 = *(const f32x4*)p0;
        const f32x4 a1 = *(const f32x4*)(p0 + 4);
        const f32x4 b0 = *(const f32x4*)p1;
        const f32x4 b1 = *(const f32x4*)(p1 + 4);
        s16x8 pk;
        #pragma unroll
        for (int j = 0; j < 4; ++j) {
            pk[j]     = (short)f2bf((a0[j] + b0[j]) * rv);
            pk[4 + j] = (short)f2bf((a1[j] + b1[j]) * rv);
        }
        *(s16x8*)&Os[row * 264 + col] = pk;
    }
    stage_64x256(Ws, wproj_bf + (size_t)cg0 * NC, tid);
    __syncthreads();

    bf16x8 a[8];
    #pragma unroll
    for (int kt = 0; kt < 8; ++kt)
        a[kt] = *(const bf16x8*)&Ws[(16 * w + c) * 264 + kt * 32 + q4 * 8];

    f32x4 acc[4];
    #pragma unroll
    for (int nt = 0; nt < 4; ++nt)
        #pragma unroll
        for (int r = 0; r < 4; ++r) acc[nt][r] = 0.f;

    #pragma unroll
    for (int nt = 0; nt < 4; ++nt)
        #pragma unroll
        for (int kt = 0; kt < 8; ++kt) {
            const bf16x8 bb = *(const bf16x8*)&Os[(16 * nt + c) * 264 + kt * 32 + q4 * 8];
            acc[nt] = __builtin_amdgcn_mfma_f32_16x16x32_bf16(a[kt], bb, acc[nt], 0, 0, 0);
        }

    #pragma unroll
    for (int nt = 0; nt < 4; ++nt)
        #pragma unroll
        for (int r = 0; r < 4; ++r) {
            const int cg = cg0 + 16 * w + 4 * q4 + r;
            out[((size_t)b * NC + cg) * NT + n0 + 16 * nt + c] = acc[nt][r] + b_proj[cg];
        }
}

// ---------------------------------------------------------------------------
extern "C" void kernel_launch(void* const* d_in, const int* in_sizes, int n_in,
                              void* d_out, int out_size, void* d_ws, size_t ws_size,
                              hipStream_t stream)
{
    const float* x      = (const float*)d_in[0];
    const float* ln_g   = (const float*)d_in[1];
    const float* ln_b   = (const float*)d_in[2];
    const float* w_qkv  = (const float*)d_in[3];
    const float* w_proj = (const float*)d_in[4];
    const float* b_proj = (const float*)d_in[5];
    float* out = (float*)d_out;

    const size_t TEN = (size_t)NB * NHEADS * NT * DH;   // 4,194,304 elements

    // f32 region first (alignment), then bf16 region.  Total ~58.9 MB.
    float* ws32 = (float*)d_ws;
    float* o_part = ws32;                                // 8,388,608 f32
    float* l_part = ws32 + 8388608;                      // 131,072 f32
    unsigned short* ws16 = (unsigned short*)(l_part + 131072);
    unsigned short* q_bf    = ws16;
    unsigned short* k_bf    = ws16 + TEN;
    unsigned short* v_bf    = ws16 + 2 * TEN;
    unsigned short* wqkv_t  = ws16 + 3 * TEN;            // [768][256]
    unsigned short* wproj_b = wqkv_t + 768 * 256;        // [256][256]

    k_prep<<<80, 256, 0, stream>>>(w_qkv, w_proj, wqkv_t, wproj_b);
    k_ln_qkv<<<dim3(NB * 64, 3), 256, 0, stream>>>(x, ln_g, ln_b, wqkv_t, q_bf, k_bf, v_bf);
    k_attn<<<16 * 64, 256, 0, stream>>>(q_bf, k_bf, v_bf, o_part, l_part);
    k_proj<<<dim3(NB * 64, 4), 256, 0, stream>>>(o_part, l_part, wproj_b, b_proj, out);
}

// Round 9
// 204.680 us; speedup vs baseline: 1.0894x; 1.0894x over previous
//
#include <hip/hip_runtime.h>
#include <math.h>

#define NB 4
#define NC 256
#define NHEADS 4
#define DH 64
#define NT 4096            // 64*64 tokens per batch
// q pre-scale with log2(e) folded in: exp(s/8) == exp2(s * QSCALE)
#define QSCALE (0.125f * 1.44269504088896f)

typedef __bf16  bf16x8 __attribute__((ext_vector_type(8)));
typedef __bf16  bf16x4 __attribute__((ext_vector_type(4)));
typedef float   f32x4  __attribute__((ext_vector_type(4)));
typedef short   s16x8  __attribute__((ext_vector_type(8)));

static __device__ __forceinline__ unsigned short f2bf(float f) {
    unsigned u = __float_as_uint(f);
    u = (u + 0x7fffu + ((u >> 16) & 1u)) >> 16;   // round-to-nearest-even
    return (unsigned short)u;
}

// single v_exp_f32 (libm exp2f expands to a multi-inst guarded sequence)
static __device__ __forceinline__ float fast_exp2(float x) {
    return __builtin_amdgcn_exp2f(x);
}

// async 16B/lane global -> LDS (DMA, no VGPR round-trip).
static __device__ __forceinline__ void gload16(const unsigned short* g, unsigned short* l) {
    __builtin_amdgcn_global_load_lds((const __attribute__((address_space(1))) void*)g,
                                     (__attribute__((address_space(3))) void*)l, 16, 0, 0);
}

// Stage 64 rows x 256 bf16 (global row stride 256 elems) -> LDS stride 264.
static __device__ __forceinline__ void stage_64x256(
    unsigned short* __restrict__ lds, const unsigned short* __restrict__ g, int tid)
{
    #pragma unroll
    for (int chunk = 0; chunk < 8; ++chunk) {
        const int row = chunk * 8 + (tid >> 5);
        const int col = (tid & 31) * 8;
        *(s16x8*)&lds[row * 264 + col] = *(const s16x8*)&g[row * 256 + col];
    }
}

// ---------------------------------------------------------------------------
// Kernel 0: weight prep (unchanged).
// ---------------------------------------------------------------------------
__global__ __launch_bounds__(256) void k_prep(
    const float* __restrict__ wqkv, const float* __restrict__ wproj,
    unsigned short* __restrict__ wqkv_t, unsigned short* __restrict__ wproj_bf)
{
    const int id = blockIdx.x;
    const int tid = threadIdx.x;
    if (id < 48) {
        __shared__ float T[64][65];
        const int jt = id % 12, ct = id / 12;
        #pragma unroll
        for (int p = 0; p < 16; ++p) {
            const int idx = tid + (p << 8);
            const int r = idx >> 6, cl = idx & 63;
            T[r][cl] = wqkv[(size_t)(ct * 64 + r) * 768 + jt * 64 + cl];
        }
        __syncthreads();
        #pragma unroll
        for (int p = 0; p < 16; ++p) {
            const int idx = tid + (p << 8);
            const int r = idx >> 6, cl = idx & 63;
            wqkv_t[(size_t)(jt * 64 + r) * 256 + ct * 64 + cl] = f2bf(T[cl][r]);
        }
    } else {
        const int base = (id - 48) * 2048 + tid * 8;
        s16x8 v;
        #pragma unroll
        for (int j = 0; j < 8; ++j) v[j] = (short)f2bf(wproj[base + j]);
        *(s16x8*)&wproj_bf[base] = v;
    }
}

// ---------------------------------------------------------------------------
// Kernel 1: LayerNorm + QKV GEMM via bf16 MFMA. (unchanged from R8)
// ---------------------------------------------------------------------------
__global__ __launch_bounds__(256) void k_ln_qkv(
    const float* __restrict__ x,       // [B][C][N]
    const float* __restrict__ ln_g,
    const float* __restrict__ ln_b,
    const unsigned short* __restrict__ wqkv_t,  // [768][256] bf16
    unsigned short* __restrict__ q_bf,
    unsigned short* __restrict__ k_bf,
    unsigned short* __restrict__ v_bf)
{
    __shared__ unsigned short An[64 * 264];
    __shared__ unsigned short Wt[64 * 264];
    __shared__ float red1[4][64], red2[4][64];
    __shared__ float mu_s[64], rs_s[64];

    const int b     = blockIdx.x >> 6;
    const int n0    = (blockIdx.x & 63) << 6;
    const int three = blockIdx.y;
    const int tid   = threadIdx.x;
    const int li    = tid & 63;
    const int grp   = tid >> 6;
    const int w     = grp;
    const int lane  = li;
    const int q4    = lane >> 4;
    const int c     = lane & 15;

    const float* xb = x + ((size_t)b * NC) * NT + n0 + li;

    float xr[64];
    #pragma unroll
    for (int chunk = 0; chunk < 8; ++chunk)
        #pragma unroll
        for (int j = 0; j < 8; ++j)
            xr[chunk * 8 + j] = xb[(size_t)(chunk * 32 + grp * 8 + j) * NT];

    float s1 = 0.f, s2 = 0.f;
    #pragma unroll
    for (int i = 0; i < 64; ++i) { s1 += xr[i]; s2 += xr[i] * xr[i]; }
    red1[grp][li] = s1; red2[grp][li] = s2;
    __syncthreads();
    if (tid < 64) {
        const float t1 = red1[0][tid] + red1[1][tid] + red1[2][tid] + red1[3][tid];
        const float t2 = red2[0][tid] + red2[1][tid] + red2[2][tid] + red2[3][tid];
        const float mu  = t1 * (1.0f / NC);
        const float var = t2 * (1.0f / NC) - mu * mu;
        mu_s[tid] = mu;
        rs_s[tid] = rsqrtf(var + 1e-5f);
    }
    __syncthreads();
    const float mu = mu_s[li];
    const float rs = rs_s[li];

    #pragma unroll
    for (int chunk = 0; chunk < 8; ++chunk) {
        s16x8 pk;
        #pragma unroll
        for (int j = 0; j < 8; ++j) {
            const int ch = chunk * 32 + grp * 8 + j;
            const float vv = (xr[chunk * 8 + j] - mu) * rs * ln_g[ch] + ln_b[ch];
            pk[j] = (short)f2bf(vv);
        }
        *(s16x8*)&An[li * 264 + chunk * 32 + grp * 8] = pk;
    }
    __syncthreads();

    bf16x8 aT[8];
    if (three < 2) {
        #pragma unroll
        for (int kt = 0; kt < 8; ++kt)
            aT[kt] = *(const bf16x8*)&An[(16 * w + c) * 264 + kt * 32 + q4 * 8];
    }

    for (int jt = 0; jt < 4; ++jt) {
        __syncthreads();
        stage_64x256(Wt, wqkv_t + (size_t)(three * 256 + jt * 64) * 256, tid);
        __syncthreads();

        f32x4 acc[4];
        #pragma unroll
        for (int nt = 0; nt < 4; ++nt)
            #pragma unroll
            for (int r = 0; r < 4; ++r) acc[nt][r] = 0.f;

        const int bh = b * NHEADS + jt;
        if (three < 2) {
            #pragma unroll
            for (int nt = 0; nt < 4; ++nt)
                #pragma unroll
                for (int kt = 0; kt < 8; ++kt) {
                    const bf16x8 bb = *(const bf16x8*)&Wt[(16 * nt + c) * 264 + kt * 32 + q4 * 8];
                    acc[nt] = __builtin_amdgcn_mfma_f32_16x16x32_bf16(aT[kt], bb, acc[nt], 0, 0, 0);
                }
            unsigned short* dst = (three == 0 ? q_bf : k_bf) + ((size_t)bh * NT + n0) * DH;
            const float sc = (three == 0) ? QSCALE : 1.0f;
            #pragma unroll
            for (int nt = 0; nt < 4; ++nt)
                #pragma unroll
                for (int r = 0; r < 4; ++r)
                    dst[(size_t)(16 * w + 4 * q4 + r) * DH + 16 * nt + c] = f2bf(acc[nt][r] * sc);
        } else {
            bf16x8 aW[8];
            #pragma unroll
            for (int kt = 0; kt < 8; ++kt)
                aW[kt] = *(const bf16x8*)&Wt[(16 * w + c) * 264 + kt * 32 + q4 * 8];
            #pragma unroll
            for (int nt = 0; nt < 4; ++nt)
                #pragma unroll
                for (int kt = 0; kt < 8; ++kt) {
                    const bf16x8 bb = *(const bf16x8*)&An[(16 * nt + c) * 264 + kt * 32 + q4 * 8];
                    acc[nt] = __builtin_amdgcn_mfma_f32_16x16x32_bf16(aW[kt], bb, acc[nt], 0, 0, 0);
                }
            unsigned short* dst = v_bf + (size_t)bh * DH * NT;
            #pragma unroll
            for (int nt = 0; nt < 4; ++nt)
                #pragma unroll
                for (int r = 0; r < 4; ++r)
                    dst[(size_t)(16 * w + 4 * q4 + r) * NT + n0 + 16 * nt + c] = f2bf(acc[nt][r]);
        }
    }
}

// ---------------------------------------------------------------------------
// Kernel 2: split-K bf16-MFMA flash attention, S^T formulation, double-
// buffered async DMA staging. ONLY change vs R8: exp2f -> v_exp_f32.
// grid = 16 bh * 32 qtiles * 2 khalf = 1024 blocks.
// LDS: K 2*8KB + V 2*8KB + Ps(bf16 128x72) 18432 = 50176 B.
// ---------------------------------------------------------------------------
__global__ __launch_bounds__(256, 2) void k_attn(
    const unsigned short* __restrict__ qg,  // [bh][n][d], pre-scaled by QSCALE
    const unsigned short* __restrict__ kg,  // [bh][n][d]
    const unsigned short* __restrict__ vg,  // [bh][d][n]  (transposed)
    float* __restrict__ o_part,             // [2][16][4096][64] f32, unnormalized
    float* __restrict__ l_part)             // [2][16][4096] f32
{
    __shared__ unsigned short Ks[2 * 4096];
    __shared__ unsigned short Vt[2 * 4096];
    __shared__ __bf16 Ps[128 * 72];

    const int bh   = blockIdx.x >> 6;          // 0..15
    const int rest = blockIdx.x & 63;
    const int qt   = rest >> 1;                // 0..31
    const int kh   = rest & 1;                 // K half
    const int n0   = qt << 7;                  // 128-query tile base
    const int tid  = threadIdx.x;
    const int w    = tid >> 6;                 // wave -> query rows 32w..32w+31
    const int lane = tid & 63;
    const int q4   = lane >> 4;
    const int c    = lane & 15;

    const unsigned short* kb = kg + ((size_t)bh * NT + (kh << 11)) * DH;
    const unsigned short* vb = vg + (size_t)bh * DH * NT + (kh << 11);

    // ---- Q frags direct from global (lane&15 = query, 8 d-elems each) ----
    bf16x8 aq[2][2];
    {
        const unsigned short* qp = qg + ((size_t)bh * NT + n0) * DH;
        #pragma unroll
        for (int g = 0; g < 2; ++g) {
            const unsigned short* qrow = qp + (size_t)(32 * w + 16 * g + c) * DH;
            aq[g][0] = *(const bf16x8*)(qrow + q4 * 8);
            aq[g][1] = *(const bf16x8*)(qrow + 32 + q4 * 8);
        }
    }

    // ---- staging lane geometry (per 1KB DMA instruction) ----
    const int rr = lane >> 3;                  // row within 8-row group
    const int kc = (lane & 7) ^ rr;            // swizzled 16B-chunk column
    const int koffK = rr * DH + kc * 8;

    // ---- swizzled frag-read offsets ----
    const int sw0 = ((q4    ) ^ (c & 7)) * 8;  // chunk q4   (d 0..31)
    const int sw1 = ((q4 + 4) ^ (c & 7)) * 8;  // chunk q4+4 (d 32..63)

    #define ISSUE_TILE(it_, bi_)                                               \
        {                                                                      \
            const unsigned short* ktp = kb + (size_t)(it_) * 64 * DH;          \
            const unsigned short* vtp = vb + (size_t)(it_) * 64;               \
            _Pragma("unroll")                                                  \
            for (int t = 0; t < 2; ++t) {                                      \
                const int grp_ = w * 2 + t;                                    \
                gload16(ktp + grp_ * 512 + koffK,                              \
                        &Ks[(bi_) * 4096 + grp_ * 512 + lane * 8]);            \
                gload16(vtp + (size_t)(grp_ * 8 + rr) * NT + kc * 8,           \
                        &Vt[(bi_) * 4096 + grp_ * 512 + lane * 8]);            \
            }                                                                  \
        }

    ISSUE_TILE(0, 0)

    f32x4 oac[2][4];
    #pragma unroll
    for (int g = 0; g < 2; ++g)
        #pragma unroll
        for (int dt = 0; dt < 4; ++dt)
            #pragma unroll
            for (int r = 0; r < 4; ++r) oac[g][dt][r] = 0.f;
    float lsum[2][4] = {};   // per-lane l partials (query c, keys {16nt+4q4+r})

    for (int it = 0; it < 32; ++it) {
        const int cur = it & 1;
        asm volatile("s_waitcnt vmcnt(0)\n\ts_barrier" ::: "memory");
        if (it < 31) ISSUE_TILE(it + 1, cur ^ 1)

        const unsigned short* Kb = &Ks[cur * 4096];
        const unsigned short* Vb = &Vt[cur * 4096];

        // ---- S^T = K Q^T: A = K-frag (m=key), B = Q-frag (n=query) ----
        f32x4 st[2][4];
        #pragma unroll
        for (int nt = 0; nt < 4; ++nt) {
            const bf16x8 kf0 = *(const bf16x8*)&Kb[(16 * nt + c) * 64 + sw0];
            const bf16x8 kf1 = *(const bf16x8*)&Kb[(16 * nt + c) * 64 + sw1];
            #pragma unroll
            for (int g = 0; g < 2; ++g) {
                f32x4 acc;
                #pragma unroll
                for (int r = 0; r < 4; ++r) acc[r] = 0.f;
                acc = __builtin_amdgcn_mfma_f32_16x16x32_bf16(kf0, aq[g][0], acc, 0, 0, 0);
                acc = __builtin_amdgcn_mfma_f32_16x16x32_bf16(kf1, aq[g][1], acc, 0, 0, 0);
                st[g][nt] = acc;
            }
        }

        // ---- P = exp2(S) via v_exp_f32; pack 4 keys -> one ds_write_b64 ----
        #pragma unroll
        for (int g = 0; g < 2; ++g)
            #pragma unroll
            for (int nt = 0; nt < 4; ++nt) {
                bf16x4 pk;
                #pragma unroll
                for (int r = 0; r < 4; ++r) {
                    const float e = fast_exp2(st[g][nt][r]);
                    lsum[g][nt] += e;
                    pk[r] = (__bf16)e;
                }
                *(bf16x4*)&Ps[(32 * w + 16 * g + c) * 72 + 16 * nt + 4 * q4] = pk;
            }

        // ---- PV: A = P (m=query, b128 rows), B = V^T frags (shared) ----
        bf16x8 pa[2][2];
        #pragma unroll
        for (int g = 0; g < 2; ++g) {
            const __bf16* prow = &Ps[(32 * w + 16 * g + c) * 72];
            pa[g][0] = *(const bf16x8*)(prow + q4 * 8);
            pa[g][1] = *(const bf16x8*)(prow + 32 + q4 * 8);
        }
        #pragma unroll
        for (int dt = 0; dt < 4; ++dt) {
            const bf16x8 v0 = *(const bf16x8*)&Vb[(16 * dt + c) * 64 + sw0];
            const bf16x8 v1 = *(const bf16x8*)&Vb[(16 * dt + c) * 64 + sw1];
            #pragma unroll
            for (int g = 0; g < 2; ++g) {
                oac[g][dt] = __builtin_amdgcn_mfma_f32_16x16x32_bf16(pa[g][0], v0, oac[g][dt], 0, 0, 0);
                oac[g][dt] = __builtin_amdgcn_mfma_f32_16x16x32_bf16(pa[g][1], v1, oac[g][dt], 0, 0, 0);
            }
        }
    }
    #undef ISSUE_TILE

    // ---- write unnormalized partial O (f32) and per-query l partial ----
    float* op = o_part + (((size_t)kh * 16 + bh) * NT + n0 + 32 * w) * DH;
    #pragma unroll
    for (int g = 0; g < 2; ++g)
        #pragma unroll
        for (int dt = 0; dt < 4; ++dt)
            #pragma unroll
            for (int r = 0; r < 4; ++r)
                op[(size_t)(16 * g + 4 * q4 + r) * DH + 16 * dt + c] = oac[g][dt][r];

    float* lp = l_part + ((size_t)kh * 16 + bh) * NT + n0 + 32 * w;
    #pragma unroll
    for (int g = 0; g < 2; ++g) {
        float t = (lsum[g][0] + lsum[g][1]) + (lsum[g][2] + lsum[g][3]);
        t += __shfl_xor(t, 16);
        t += __shfl_xor(t, 32);
        if (q4 == 0) lp[16 * g + c] = t;     // lanes 0..15 -> 16 consecutive f32
    }
}

// ---------------------------------------------------------------------------
// Kernel 3: output projection via bf16 MFMA with fused split-K combine.
// (unchanged from R8)
// ---------------------------------------------------------------------------
__global__ __launch_bounds__(256) void k_proj(
    const float* __restrict__ o_part,            // [2][16][4096][64] f32
    const float* __restrict__ l_part,            // [2][16][4096] f32
    const unsigned short* __restrict__ wproj_bf, // [256][256] bf16
    const float* __restrict__ b_proj,
    float* __restrict__ out)                     // [B][C][N]
{
    __shared__ unsigned short Os[64 * 264];
    __shared__ unsigned short Ws[64 * 264];

    const int b   = blockIdx.x >> 6;
    const int n0  = (blockIdx.x & 63) << 6;
    const int cg0 = blockIdx.y << 6;
    const int tid = threadIdx.x;
    const int w   = tid >> 6;
    const int lane = tid & 63;
    const int q4  = lane >> 4;
    const int c   = lane & 15;

    const size_t OPS = (size_t)16 * NT * DH;     // o_part kh-stride
    const size_t LPS = (size_t)16 * NT;          // l_part kh-stride

    #pragma unroll
    for (int chunk = 0; chunk < 8; ++chunk) {
        const int row = chunk * 8 + (tid >> 5);
        const int col = (tid & 31) * 8;
        const int hd  = col >> 6;
        const int c64 = col & 63;
        const size_t tok = (size_t)(b * NHEADS + hd) * NT + n0 + row;
        const float rv = 1.0f / (l_part[tok] + l_part[LPS + tok]);
        const float* p0 = o_part + tok * DH + c64;
        const float* p1 = p0 + OPS;
        const f32x4 a0 = *(const f32x4*)p0;
        const f32x4 a1 = *(const f32x4*)(p0 + 4);
        const f32x4 b0 = *(const f32x4*)p1;
        const f32x4 b1 = *(const f32x4*)(p1 + 4);
        s16x8 pk;
        #pragma unroll
        for (int j = 0; j < 4; ++j) {
            pk[j]     = (short)f2bf((a0[j] + b0[j]) * rv);
            pk[4 + j] = (short)f2bf((a1[j] + b1[j]) * rv);
        }
        *(s16x8*)&Os[row * 264 + col] = pk;
    }
    stage_64x256(Ws, wproj_bf + (size_t)cg0 * NC, tid);
    __syncthreads();

    bf16x8 a[8];
    #pragma unroll
    for (int kt = 0; kt < 8; ++kt)
        a[kt] = *(const bf16x8*)&Ws[(16 * w + c) * 264 + kt * 32 + q4 * 8];

    f32x4 acc[4];
    #pragma unroll
    for (int nt = 0; nt < 4; ++nt)
        #pragma unroll
        for (int r = 0; r < 4; ++r) acc[nt][r] = 0.f;

    #pragma unroll
    for (int nt = 0; nt < 4; ++nt)
        #pragma unroll
        for (int kt = 0; kt < 8; ++kt) {
            const bf16x8 bb = *(const bf16x8*)&Os[(16 * nt + c) * 264 + kt * 32 + q4 * 8];
            acc[nt] = __builtin_amdgcn_mfma_f32_16x16x32_bf16(a[kt], bb, acc[nt], 0, 0, 0);
        }

    #pragma unroll
    for (int nt = 0; nt < 4; ++nt)
        #pragma unroll
        for (int r = 0; r < 4; ++r) {
            const int cg = cg0 + 16 * w + 4 * q4 + r;
            out[((size_t)b * NC + cg) * NT + n0 + 16 * nt + c] = acc[nt][r] + b_proj[cg];
        }
}

// ---------------------------------------------------------------------------
extern "C" void kernel_launch(void* const* d_in, const int* in_sizes, int n_in,
                              void* d_out, int out_size, void* d_ws, size_t ws_size,
                              hipStream_t stream)
{
    const float* x      = (const float*)d_in[0];
    const float* ln_g   = (const float*)d_in[1];
    const float* ln_b   = (const float*)d_in[2];
    const float* w_qkv  = (const float*)d_in[3];
    const float* w_proj = (const float*)d_in[4];
    const float* b_proj = (const float*)d_in[5];
    float* out = (float*)d_out;

    const size_t TEN = (size_t)NB * NHEADS * NT * DH;   // 4,194,304 elements

    float* ws32 = (float*)d_ws;
    float* o_part = ws32;                                // 8,388,608 f32
    float* l_part = ws32 + 8388608;                      // 131,072 f32
    unsigned short* ws16 = (unsigned short*)(l_part + 131072);
    unsigned short* q_bf    = ws16;
    unsigned short* k_bf    = ws16 + TEN;
    unsigned short* v_bf    = ws16 + 2 * TEN;
    unsigned short* wqkv_t  = ws16 + 3 * TEN;            // [768][256]
    unsigned short* wproj_b = wqkv_t + 768 * 256;        // [256][256]

    k_prep<<<80, 256, 0, stream>>>(w_qkv, w_proj, wqkv_t, wproj_b);
    k_ln_qkv<<<dim3(NB * 64, 3), 256, 0, stream>>>(x, ln_g, ln_b, wqkv_t, q_bf, k_bf, v_bf);
    k_attn<<<16 * 64, 256, 0, stream>>>(q_bf, k_bf, v_bf, o_part, l_part);
    k_proj<<<dim3(NB * 64, 4), 256, 0, stream>>>(o_part, l_part, wproj_b, b_proj, out);
}

// Round 10
// 192.257 us; speedup vs baseline: 1.1597x; 1.0646x over previous
//
#include <hip/hip_runtime.h>
#include <math.h>

#define NB 4
#define NC 256
#define NHEADS 4
#define DH 64
#define NT 4096            // 64*64 tokens per batch
// q pre-scale with log2(e) folded in: exp(s/8) == exp2(s * QSCALE)
#define QSCALE (0.125f * 1.44269504088896f)

typedef __bf16  bf16x8 __attribute__((ext_vector_type(8)));
typedef __bf16  bf16x4 __attribute__((ext_vector_type(4)));
typedef float   f32x4  __attribute__((ext_vector_type(4)));
typedef short   s16x8  __attribute__((ext_vector_type(8)));

static __device__ __forceinline__ unsigned short f2bf(float f) {
    unsigned u = __float_as_uint(f);
    u = (u + 0x7fffu + ((u >> 16) & 1u)) >> 16;   // round-to-nearest-even
    return (unsigned short)u;
}

// single v_exp_f32 (libm exp2f expands to a multi-inst guarded sequence)
static __device__ __forceinline__ float fast_exp2(float x) {
    return __builtin_amdgcn_exp2f(x);
}

// async 16B/lane global -> LDS (DMA, no VGPR round-trip).
static __device__ __forceinline__ void gload16(const unsigned short* g, unsigned short* l) {
    __builtin_amdgcn_global_load_lds((const __attribute__((address_space(1))) void*)g,
                                     (__attribute__((address_space(3))) void*)l, 16, 0, 0);
}

// Stage 64 rows x 256 bf16 (global row stride 256 elems) -> LDS stride 264.
static __device__ __forceinline__ void stage_64x256(
    unsigned short* __restrict__ lds, const unsigned short* __restrict__ g, int tid)
{
    #pragma unroll
    for (int chunk = 0; chunk < 8; ++chunk) {
        const int row = chunk * 8 + (tid >> 5);
        const int col = (tid & 31) * 8;
        *(s16x8*)&lds[row * 264 + col] = *(const s16x8*)&g[row * 256 + col];
    }
}

// ---------------------------------------------------------------------------
// Kernel 0: weight prep (unchanged).
// ---------------------------------------------------------------------------
__global__ __launch_bounds__(256) void k_prep(
    const float* __restrict__ wqkv, const float* __restrict__ wproj,
    unsigned short* __restrict__ wqkv_t, unsigned short* __restrict__ wproj_bf)
{
    const int id = blockIdx.x;
    const int tid = threadIdx.x;
    if (id < 48) {
        __shared__ float T[64][65];
        const int jt = id % 12, ct = id / 12;
        #pragma unroll
        for (int p = 0; p < 16; ++p) {
            const int idx = tid + (p << 8);
            const int r = idx >> 6, cl = idx & 63;
            T[r][cl] = wqkv[(size_t)(ct * 64 + r) * 768 + jt * 64 + cl];
        }
        __syncthreads();
        #pragma unroll
        for (int p = 0; p < 16; ++p) {
            const int idx = tid + (p << 8);
            const int r = idx >> 6, cl = idx & 63;
            wqkv_t[(size_t)(jt * 64 + r) * 256 + ct * 64 + cl] = f2bf(T[cl][r]);
        }
    } else {
        const int base = (id - 48) * 2048 + tid * 8;
        s16x8 v;
        #pragma unroll
        for (int j = 0; j < 8; ++j) v[j] = (short)f2bf(wproj[base + j]);
        *(s16x8*)&wproj_bf[base] = v;
    }
}

// ---------------------------------------------------------------------------
// Kernel 1: LayerNorm + QKV GEMM via bf16 MFMA. (unchanged from R9)
// ---------------------------------------------------------------------------
__global__ __launch_bounds__(256) void k_ln_qkv(
    const float* __restrict__ x,       // [B][C][N]
    const float* __restrict__ ln_g,
    const float* __restrict__ ln_b,
    const unsigned short* __restrict__ wqkv_t,  // [768][256] bf16
    unsigned short* __restrict__ q_bf,
    unsigned short* __restrict__ k_bf,
    unsigned short* __restrict__ v_bf)
{
    __shared__ unsigned short An[64 * 264];
    __shared__ unsigned short Wt[64 * 264];
    __shared__ float red1[4][64], red2[4][64];
    __shared__ float mu_s[64], rs_s[64];

    const int b     = blockIdx.x >> 6;
    const int n0    = (blockIdx.x & 63) << 6;
    const int three = blockIdx.y;
    const int tid   = threadIdx.x;
    const int li    = tid & 63;
    const int grp   = tid >> 6;
    const int w     = grp;
    const int lane  = li;
    const int q4    = lane >> 4;
    const int c     = lane & 15;

    const float* xb = x + ((size_t)b * NC) * NT + n0 + li;

    float xr[64];
    #pragma unroll
    for (int chunk = 0; chunk < 8; ++chunk)
        #pragma unroll
        for (int j = 0; j < 8; ++j)
            xr[chunk * 8 + j] = xb[(size_t)(chunk * 32 + grp * 8 + j) * NT];

    float s1 = 0.f, s2 = 0.f;
    #pragma unroll
    for (int i = 0; i < 64; ++i) { s1 += xr[i]; s2 += xr[i] * xr[i]; }
    red1[grp][li] = s1; red2[grp][li] = s2;
    __syncthreads();
    if (tid < 64) {
        const float t1 = red1[0][tid] + red1[1][tid] + red1[2][tid] + red1[3][tid];
        const float t2 = red2[0][tid] + red2[1][tid] + red2[2][tid] + red2[3][tid];
        const float mu  = t1 * (1.0f / NC);
        const float var = t2 * (1.0f / NC) - mu * mu;
        mu_s[tid] = mu;
        rs_s[tid] = rsqrtf(var + 1e-5f);
    }
    __syncthreads();
    const float mu = mu_s[li];
    const float rs = rs_s[li];

    #pragma unroll
    for (int chunk = 0; chunk < 8; ++chunk) {
        s16x8 pk;
        #pragma unroll
        for (int j = 0; j < 8; ++j) {
            const int ch = chunk * 32 + grp * 8 + j;
            const float vv = (xr[chunk * 8 + j] - mu) * rs * ln_g[ch] + ln_b[ch];
            pk[j] = (short)f2bf(vv);
        }
        *(s16x8*)&An[li * 264 + chunk * 32 + grp * 8] = pk;
    }
    __syncthreads();

    bf16x8 aT[8];
    if (three < 2) {
        #pragma unroll
        for (int kt = 0; kt < 8; ++kt)
            aT[kt] = *(const bf16x8*)&An[(16 * w + c) * 264 + kt * 32 + q4 * 8];
    }

    for (int jt = 0; jt < 4; ++jt) {
        __syncthreads();
        stage_64x256(Wt, wqkv_t + (size_t)(three * 256 + jt * 64) * 256, tid);
        __syncthreads();

        f32x4 acc[4];
        #pragma unroll
        for (int nt = 0; nt < 4; ++nt)
            #pragma unroll
            for (int r = 0; r < 4; ++r) acc[nt][r] = 0.f;

        const int bh = b * NHEADS + jt;
        if (three < 2) {
            #pragma unroll
            for (int nt = 0; nt < 4; ++nt)
                #pragma unroll
                for (int kt = 0; kt < 8; ++kt) {
                    const bf16x8 bb = *(const bf16x8*)&Wt[(16 * nt + c) * 264 + kt * 32 + q4 * 8];
                    acc[nt] = __builtin_amdgcn_mfma_f32_16x16x32_bf16(aT[kt], bb, acc[nt], 0, 0, 0);
                }
            unsigned short* dst = (three == 0 ? q_bf : k_bf) + ((size_t)bh * NT + n0) * DH;
            const float sc = (three == 0) ? QSCALE : 1.0f;
            #pragma unroll
            for (int nt = 0; nt < 4; ++nt)
                #pragma unroll
                for (int r = 0; r < 4; ++r)
                    dst[(size_t)(16 * w + 4 * q4 + r) * DH + 16 * nt + c] = f2bf(acc[nt][r] * sc);
        } else {
            bf16x8 aW[8];
            #pragma unroll
            for (int kt = 0; kt < 8; ++kt)
                aW[kt] = *(const bf16x8*)&Wt[(16 * w + c) * 264 + kt * 32 + q4 * 8];
            #pragma unroll
            for (int nt = 0; nt < 4; ++nt)
                #pragma unroll
                for (int kt = 0; kt < 8; ++kt) {
                    const bf16x8 bb = *(const bf16x8*)&An[(16 * nt + c) * 264 + kt * 32 + q4 * 8];
                    acc[nt] = __builtin_amdgcn_mfma_f32_16x16x32_bf16(aW[kt], bb, acc[nt], 0, 0, 0);
                }
            unsigned short* dst = v_bf + (size_t)bh * DH * NT;
            #pragma unroll
            for (int nt = 0; nt < 4; ++nt)
                #pragma unroll
                for (int r = 0; r < 4; ++r)
                    dst[(size_t)(16 * w + 4 * q4 + r) * NT + n0 + 16 * nt + c] = f2bf(acc[nt][r]);
        }
    }
}

// ---------------------------------------------------------------------------
// Kernel 2: split-K bf16-MFMA flash attention, S^T formulation, 64 QUERIES
// PER WAVE (4 groups of 16): K/V frag reads amortized over 2x the MFMA work
// vs R9 -> per-CU LDS traffic for K/V halves. exp fused into the nt-loop
// (st never materializes as an array -> VGPR ~170). Double-buffered async
// DMA staging, one fused vmcnt(0);s_barrier per iter. Max-free softmax.
// grid = 16 bh * 16 qtiles * 2 khalf = 512 blocks, 256 threads.
// LDS: K 2*8KB + V 2*8KB + Ps(bf16 256x72) 36864 = 69632 B -> 2 blocks/CU.
// ---------------------------------------------------------------------------
__global__ __launch_bounds__(256, 2) void k_attn(
    const unsigned short* __restrict__ qg,  // [bh][n][d], pre-scaled by QSCALE
    const unsigned short* __restrict__ kg,  // [bh][n][d]
    const unsigned short* __restrict__ vg,  // [bh][d][n]  (transposed)
    float* __restrict__ o_part,             // [2][16][4096][64] f32, unnormalized
    float* __restrict__ l_part)             // [2][16][4096] f32
{
    __shared__ unsigned short Ks[2 * 4096];
    __shared__ unsigned short Vt[2 * 4096];
    __shared__ __bf16 Ps[256 * 72];

    const int bh   = blockIdx.x >> 5;          // 0..15
    const int rest = blockIdx.x & 31;
    const int qt   = rest >> 1;                // 0..15
    const int kh   = rest & 1;                 // K half
    const int n0   = qt << 8;                  // 256-query tile base
    const int tid  = threadIdx.x;
    const int w    = tid >> 6;                 // wave -> query rows 64w..64w+63
    const int lane = tid & 63;
    const int q4   = lane >> 4;
    const int c    = lane & 15;

    const unsigned short* kb = kg + ((size_t)bh * NT + (kh << 11)) * DH;
    const unsigned short* vb = vg + (size_t)bh * DH * NT + (kh << 11);

    // ---- Q frags direct from global: 4 groups of 16 queries ----
    bf16x8 aq[4][2];
    {
        const unsigned short* qp = qg + ((size_t)bh * NT + n0) * DH;
        #pragma unroll
        for (int g = 0; g < 4; ++g) {
            const unsigned short* qrow = qp + (size_t)(64 * w + 16 * g + c) * DH;
            aq[g][0] = *(const bf16x8*)(qrow + q4 * 8);
            aq[g][1] = *(const bf16x8*)(qrow + 32 + q4 * 8);
        }
    }

    // ---- staging lane geometry (per 1KB DMA instruction) ----
    const int rr = lane >> 3;                  // row within 8-row group
    const int kc = (lane & 7) ^ rr;            // swizzled 16B-chunk column
    const int koffK = rr * DH + kc * 8;

    // ---- swizzled frag-read offsets ----
    const int sw0 = ((q4    ) ^ (c & 7)) * 8;  // chunk q4   (d 0..31)
    const int sw1 = ((q4 + 4) ^ (c & 7)) * 8;  // chunk q4+4 (d 32..63)

    #define ISSUE_TILE(it_, bi_)                                               \
        {                                                                      \
            const unsigned short* ktp = kb + (size_t)(it_) * 64 * DH;          \
            const unsigned short* vtp = vb + (size_t)(it_) * 64;               \
            _Pragma("unroll")                                                  \
            for (int t = 0; t < 2; ++t) {                                      \
                const int grp_ = w * 2 + t;                                    \
                gload16(ktp + grp_ * 512 + koffK,                              \
                        &Ks[(bi_) * 4096 + grp_ * 512 + lane * 8]);            \
                gload16(vtp + (size_t)(grp_ * 8 + rr) * NT + kc * 8,           \
                        &Vt[(bi_) * 4096 + grp_ * 512 + lane * 8]);            \
            }                                                                  \
        }

    ISSUE_TILE(0, 0)

    f32x4 oac[4][4];
    #pragma unroll
    for (int g = 0; g < 4; ++g)
        #pragma unroll
        for (int dt = 0; dt < 4; ++dt)
            #pragma unroll
            for (int r = 0; r < 4; ++r) oac[g][dt][r] = 0.f;
    float lsum[4][4] = {};   // [g][nt] partial l (query c, keys {16nt+4q4+r})

    for (int it = 0; it < 32; ++it) {
        const int cur = it & 1;
        asm volatile("s_waitcnt vmcnt(0)\n\ts_barrier" ::: "memory");
        if (it < 31) ISSUE_TILE(it + 1, cur ^ 1)

        const unsigned short* Kb = &Ks[cur * 4096];
        const unsigned short* Vb = &Vt[cur * 4096];

        // ---- S^T = K Q^T (A=K m=key, B=Q n=query), exp fused per nt ----
        #pragma unroll
        for (int nt = 0; nt < 4; ++nt) {
            const bf16x8 kf0 = *(const bf16x8*)&Kb[(16 * nt + c) * 64 + sw0];
            const bf16x8 kf1 = *(const bf16x8*)&Kb[(16 * nt + c) * 64 + sw1];
            #pragma unroll
            for (int g = 0; g < 4; ++g) {
                f32x4 acc;
                #pragma unroll
                for (int r = 0; r < 4; ++r) acc[r] = 0.f;
                acc = __builtin_amdgcn_mfma_f32_16x16x32_bf16(kf0, aq[g][0], acc, 0, 0, 0);
                acc = __builtin_amdgcn_mfma_f32_16x16x32_bf16(kf1, aq[g][1], acc, 0, 0, 0);
                bf16x4 pk;
                #pragma unroll
                for (int r = 0; r < 4; ++r) {
                    const float e = fast_exp2(acc[r]);
                    lsum[g][nt] += e;
                    pk[r] = (__bf16)e;
                }
                *(bf16x4*)&Ps[(64 * w + 16 * g + c) * 72 + 16 * nt + 4 * q4] = pk;
            }
        }

        // ---- PV: A = P (b128 rows), B = V^T frags (shared by all groups) ----
        bf16x8 pa[4][2];
        #pragma unroll
        for (int g = 0; g < 4; ++g) {
            const __bf16* prow = &Ps[(64 * w + 16 * g + c) * 72];
            pa[g][0] = *(const bf16x8*)(prow + q4 * 8);
            pa[g][1] = *(const bf16x8*)(prow + 32 + q4 * 8);
        }
        #pragma unroll
        for (int dt = 0; dt < 4; ++dt) {
            const bf16x8 v0 = *(const bf16x8*)&Vb[(16 * dt + c) * 64 + sw0];
            const bf16x8 v1 = *(const bf16x8*)&Vb[(16 * dt + c) * 64 + sw1];
            #pragma unroll
            for (int g = 0; g < 4; ++g) {
                oac[g][dt] = __builtin_amdgcn_mfma_f32_16x16x32_bf16(pa[g][0], v0, oac[g][dt], 0, 0, 0);
                oac[g][dt] = __builtin_amdgcn_mfma_f32_16x16x32_bf16(pa[g][1], v1, oac[g][dt], 0, 0, 0);
            }
        }
    }
    #undef ISSUE_TILE

    // ---- write unnormalized partial O (f32) and per-query l partial ----
    float* op = o_part + (((size_t)kh * 16 + bh) * NT + n0 + 64 * w) * DH;
    #pragma unroll
    for (int g = 0; g < 4; ++g)
        #pragma unroll
        for (int dt = 0; dt < 4; ++dt)
            #pragma unroll
            for (int r = 0; r < 4; ++r)
                op[(size_t)(16 * g + 4 * q4 + r) * DH + 16 * dt + c] = oac[g][dt][r];

    float* lp = l_part + ((size_t)kh * 16 + bh) * NT + n0 + 64 * w;
    #pragma unroll
    for (int g = 0; g < 4; ++g) {
        float t = (lsum[g][0] + lsum[g][1]) + (lsum[g][2] + lsum[g][3]);
        t += __shfl_xor(t, 16);
        t += __shfl_xor(t, 32);
        if (q4 == 0) lp[16 * g + c] = t;     // lanes 0..15 -> 16 consecutive f32
    }
}

// ---------------------------------------------------------------------------
// Kernel 3: output projection via bf16 MFMA with fused split-K combine.
// R10 change: grid (256, 2) with internal ct-loop over 2 cg tiles -> the
// combined-O staging (o_part reads + normalize) happens HALF as often.
// ---------------------------------------------------------------------------
__global__ __launch_bounds__(256) void k_proj(
    const float* __restrict__ o_part,            // [2][16][4096][64] f32
    const float* __restrict__ l_part,            // [2][16][4096] f32
    const unsigned short* __restrict__ wproj_bf, // [256][256] bf16
    const float* __restrict__ b_proj,
    float* __restrict__ out)                     // [B][C][N]
{
    __shared__ unsigned short Os[64 * 264];
    __shared__ unsigned short Ws[64 * 264];

    const int b   = blockIdx.x >> 6;
    const int n0  = (blockIdx.x & 63) << 6;
    const int yh  = blockIdx.y;                  // 0..1 -> cg half
    const int tid = threadIdx.x;
    const int w   = tid >> 6;
    const int lane = tid & 63;
    const int q4  = lane >> 4;
    const int c   = lane & 15;

    const size_t OPS = (size_t)16 * NT * DH;     // o_part kh-stride
    const size_t LPS = (size_t)16 * NT;          // l_part kh-stride

    // ---- stage combined O tile once: (O0+O1)/(l0+l1) -> bf16 LDS ----
    #pragma unroll
    for (int chunk = 0; chunk < 8; ++chunk) {
        const int row = chunk * 8 + (tid >> 5);
        const int col = (tid & 31) * 8;
        const int hd  = col >> 6;
        const int c64 = col & 63;
        const size_t tok = (size_t)(b * NHEADS + hd) * NT + n0 + row;
        const float rv = 1.0f / (l_part[tok] + l_part[LPS + tok]);
        const float* p0 = o_part + tok * DH + c64;
        const float* p1 = p0 + OPS;
        const f32x4 a0 = *(const f32x4*)p0;
        const f32x4 a1 = *(const f32x4*)(p0 + 4);
        const f32x4 b0 = *(const f32x4*)p1;
        const f32x4 b1 = *(const f32x4*)(p1 + 4);
        s16x8 pk;
        #pragma unroll
        for (int j = 0; j < 4; ++j) {
            pk[j]     = (short)f2bf((a0[j] + b0[j]) * rv);
            pk[4 + j] = (short)f2bf((a1[j] + b1[j]) * rv);
        }
        *(s16x8*)&Os[row * 264 + col] = pk;
    }

    for (int ct = 0; ct < 2; ++ct) {
        const int cg0 = (yh * 2 + ct) * 64;
        if (ct) __syncthreads();                 // Ws reuse guard
        stage_64x256(Ws, wproj_bf + (size_t)cg0 * NC, tid);
        __syncthreads();                         // Ws (and on ct==0, Os) visible

        bf16x8 a[8];
        #pragma unroll
        for (int kt = 0; kt < 8; ++kt)
            a[kt] = *(const bf16x8*)&Ws[(16 * w + c) * 264 + kt * 32 + q4 * 8];

        f32x4 acc[4];
        #pragma unroll
        for (int nt = 0; nt < 4; ++nt)
            #pragma unroll
            for (int r = 0; r < 4; ++r) acc[nt][r] = 0.f;

        #pragma unroll
        for (int nt = 0; nt < 4; ++nt)
            #pragma unroll
            for (int kt = 0; kt < 8; ++kt) {
                const bf16x8 bb = *(const bf16x8*)&Os[(16 * nt + c) * 264 + kt * 32 + q4 * 8];
                acc[nt] = __builtin_amdgcn_mfma_f32_16x16x32_bf16(a[kt], bb, acc[nt], 0, 0, 0);
            }

        #pragma unroll
        for (int nt = 0; nt < 4; ++nt)
            #pragma unroll
            for (int r = 0; r < 4; ++r) {
                const int cg = cg0 + 16 * w + 4 * q4 + r;
                out[((size_t)b * NC + cg) * NT + n0 + 16 * nt + c] = acc[nt][r] + b_proj[cg];
            }
    }
}

// ---------------------------------------------------------------------------
extern "C" void kernel_launch(void* const* d_in, const int* in_sizes, int n_in,
                              void* d_out, int out_size, void* d_ws, size_t ws_size,
                              hipStream_t stream)
{
    const float* x      = (const float*)d_in[0];
    const float* ln_g   = (const float*)d_in[1];
    const float* ln_b   = (const float*)d_in[2];
    const float* w_qkv  = (const float*)d_in[3];
    const float* w_proj = (const float*)d_in[4];
    const float* b_proj = (const float*)d_in[5];
    float* out = (float*)d_out;

    const size_t TEN = (size_t)NB * NHEADS * NT * DH;   // 4,194,304 elements

    float* ws32 = (float*)d_ws;
    float* o_part = ws32;                                // 8,388,608 f32
    float* l_part = ws32 + 8388608;                      // 131,072 f32
    unsigned short* ws16 = (unsigned short*)(l_part + 131072);
    unsigned short* q_bf    = ws16;
    unsigned short* k_bf    = ws16 + TEN;
    unsigned short* v_bf    = ws16 + 2 * TEN;
    unsigned short* wqkv_t  = ws16 + 3 * TEN;            // [768][256]
    unsigned short* wproj_b = wqkv_t + 768 * 256;        // [256][256]

    k_prep<<<80, 256, 0, stream>>>(w_qkv, w_proj, wqkv_t, wproj_b);
    k_ln_qkv<<<dim3(NB * 64, 3), 256, 0, stream>>>(x, ln_g, ln_b, wqkv_t, q_bf, k_bf, v_bf);
    k_attn<<<16 * 32, 256, 0, stream>>>(q_bf, k_bf, v_bf, o_part, l_part);
    k_proj<<<dim3(NB * 64, 2), 256, 0, stream>>>(o_part, l_part, wproj_b, b_proj, out);
}